// Round 1
// baseline (2412.853 us; speedup 1.0000x reference)
//
#include <hip/hip_runtime.h>

#define DEV __device__ __forceinline__

using f32x4  = __attribute__((ext_vector_type(4))) float;
using bf16x8 = __attribute__((ext_vector_type(8))) __bf16;
using bf16x4 = __attribute__((ext_vector_type(4))) __bf16;

constexpr int Bc = 8, Tc = 2048, Ec = 1024, Hc = 1024;
constexpr int Mc = Bc * Tc;  // 16384 total rows

DEV f32x4 mfma16(bf16x8 a, bf16x8 b, f32x4 c) {
    return __builtin_amdgcn_mfma_f32_16x16x32_bf16(a, b, c, 0, 0, 0);
}

DEV unsigned short f16bits(float f) {
    return __builtin_bit_cast(unsigned short, (_Float16)f);
}
DEV float f16val(unsigned short u) {
    return (float)__builtin_bit_cast(_Float16, u);
}
DEV unsigned short bf16bits(float f) {
    return __builtin_bit_cast(unsigned short, (__bf16)f);
}

// ---------------------------------------------------------------------------
// prep_x: split f32 x into hi/lo bf16 (x = hi + lo to ~17 mantissa bits)
// ---------------------------------------------------------------------------
__global__ __launch_bounds__(256) void prep_x(const float* __restrict__ x,
                                              __bf16* __restrict__ xh,
                                              __bf16* __restrict__ xl, int n) {
    int i = (blockIdx.x * 256 + threadIdx.x) * 4;
    if (i >= n) return;
    f32x4 v = *reinterpret_cast<const f32x4*>(x + i);
    bf16x4 h, l;
#pragma unroll
    for (int j = 0; j < 4; j++) {
        __bf16 hv = (__bf16)v[j];
        h[j] = hv;
        l[j] = (__bf16)(v[j] - (float)hv);
    }
    *reinterpret_cast<bf16x4*>(xh + i) = h;
    *reinterpret_cast<bf16x4*>(xl + i) = l;
}

// ---------------------------------------------------------------------------
// prep_w: transpose W[e][n] -> WT[n][e] and split hi/lo bf16 (V: hi only).
// LDS 32x32 tile transpose; blockIdx.z selects Wq/Wk/Wv.
// ---------------------------------------------------------------------------
__global__ __launch_bounds__(256) void prep_w(const float* __restrict__ wq,
                                              const float* __restrict__ wk,
                                              const float* __restrict__ wv,
                                              __bf16* __restrict__ qh, __bf16* __restrict__ ql,
                                              __bf16* __restrict__ kh, __bf16* __restrict__ kl,
                                              __bf16* __restrict__ vh) {
    __shared__ float tile[32][33];
    const int z = blockIdx.z;
    const float* src = (z == 0) ? wq : (z == 1) ? wk : wv;
    __bf16* dh = (z == 0) ? qh : (z == 1) ? kh : vh;
    __bf16* dl = (z == 0) ? ql : (z == 1) ? kl : nullptr;
    const int n0 = blockIdx.x * 32, e0 = blockIdx.y * 32;
    const int tx = threadIdx.x & 31, ty = threadIdx.x >> 5;  // 32 x 8
#pragma unroll
    for (int j = 0; j < 32; j += 8)
        tile[ty + j][tx] = src[(size_t)(e0 + ty + j) * Hc + n0 + tx];
    __syncthreads();
#pragma unroll
    for (int j = 0; j < 32; j += 8) {
        float v = tile[tx][ty + j];
        __bf16 h = (__bf16)v;
        size_t idx = (size_t)(n0 + ty + j) * Ec + e0 + tx;
        dh[idx] = h;
        if (dl) dl[idx] = (__bf16)(v - (float)h);
    }
}

// ---------------------------------------------------------------------------
// gemm_xw: C[M x 1024] = X[M x 1024] @ W.  A,B fragments direct from global
// (contiguous along K).  MODE 0 (Q/K): 3-term split, store hi/lo bf16 row-major.
// MODE 1 (V): 1-term, store transposed bf16 Vt[b][dout][t].
// Wave computes a 32x32 output tile; block = 4 waves = 128 rows.
// ---------------------------------------------------------------------------
template <int MODE>
__global__ __launch_bounds__(256) void gemm_xw(const __bf16* __restrict__ xh,
                                               const __bf16* __restrict__ xl,
                                               const __bf16* __restrict__ wh,
                                               const __bf16* __restrict__ wl,
                                               __bf16* __restrict__ oh,
                                               __bf16* __restrict__ ol) {
    const int wave = threadIdx.x >> 6, lane = threadIdx.x & 63;
    const int lr = lane & 15, lk = lane >> 4;
    const int m0 = blockIdx.y * 128 + wave * 32;
    const int n0 = blockIdx.x * 32;
    f32x4 acc[2][2] = {};
    for (int k0 = 0; k0 < Ec; k0 += 32) {
        const int kf = k0 + lk * 8;
        bf16x8 ah[2], al[2], bh[2], bl[2];
#pragma unroll
        for (int i = 0; i < 2; i++) {
            const size_t arow = (size_t)(m0 + i * 16 + lr) * Ec;
            ah[i] = *reinterpret_cast<const bf16x8*>(xh + arow + kf);
            if (MODE == 0) al[i] = *reinterpret_cast<const bf16x8*>(xl + arow + kf);
            const size_t brow = (size_t)(n0 + i * 16 + lr) * Ec;
            bh[i] = *reinterpret_cast<const bf16x8*>(wh + brow + kf);
            if (MODE == 0) bl[i] = *reinterpret_cast<const bf16x8*>(wl + brow + kf);
        }
#pragma unroll
        for (int i = 0; i < 2; i++)
#pragma unroll
            for (int j = 0; j < 2; j++) {
                acc[i][j] = mfma16(ah[i], bh[j], acc[i][j]);
                if (MODE == 0) {
                    acc[i][j] = mfma16(al[i], bh[j], acc[i][j]);
                    acc[i][j] = mfma16(ah[i], bl[j], acc[i][j]);
                }
            }
    }
#pragma unroll
    for (int i = 0; i < 2; i++)
#pragma unroll
        for (int j = 0; j < 2; j++)
#pragma unroll
            for (int r = 0; r < 4; r++) {
                const int row = m0 + i * 16 + lk * 4 + r;  // C/D: row=(lane>>4)*4+reg
                const int col = n0 + j * 16 + lr;          //      col=lane&15
                const float v = acc[i][j][r];
                if (MODE == 0) {
                    __bf16 h = (__bf16)v;
                    oh[(size_t)row * Hc + col] = h;
                    ol[(size_t)row * Hc + col] = (__bf16)(v - (float)h);
                } else {
                    const int bb = row >> 11, t = row & (Tc - 1);
                    oh[((size_t)bb * Hc + col) * Tc + t] = (__bf16)v;  // Vt[b][dout][t]
                }
            }
}

// ---------------------------------------------------------------------------
// energy_k: S[q][k] = (Q.K) * (1/sqrt(dk)) for one batch, causal tiles only,
// stored f16.  3-term split QK^T.  One wave per 32x32 tile; grid (ik, iq).
// ---------------------------------------------------------------------------
__global__ __launch_bounds__(64) void energy_k(const __bf16* __restrict__ qh,
                                               const __bf16* __restrict__ ql,
                                               const __bf16* __restrict__ kh,
                                               const __bf16* __restrict__ kl,
                                               unsigned short* __restrict__ S,
                                               const int* __restrict__ dkp, int b) {
    const int ik = blockIdx.x, iq = blockIdx.y;
    if (ik > iq) return;
    const int lane = threadIdx.x;
    const int lr = lane & 15, lk = lane >> 4;
    const size_t base = (size_t)b * Tc;
    const int q0 = iq * 32, k0c = ik * 32;
    f32x4 acc[2][2] = {};
    for (int d0 = 0; d0 < Hc; d0 += 32) {
        const int kf = d0 + lk * 8;
        bf16x8 aQh[2], aQl[2], bKh[2], bKl[2];
#pragma unroll
        for (int i = 0; i < 2; i++) {
            const size_t qrow = (base + q0 + i * 16 + lr) * Hc;
            aQh[i] = *reinterpret_cast<const bf16x8*>(qh + qrow + kf);
            aQl[i] = *reinterpret_cast<const bf16x8*>(ql + qrow + kf);
            const size_t krow = (base + k0c + i * 16 + lr) * Hc;
            bKh[i] = *reinterpret_cast<const bf16x8*>(kh + krow + kf);
            bKl[i] = *reinterpret_cast<const bf16x8*>(kl + krow + kf);
        }
#pragma unroll
        for (int i = 0; i < 2; i++)
#pragma unroll
            for (int j = 0; j < 2; j++) {
                acc[i][j] = mfma16(aQh[i], bKh[j], acc[i][j]);
                acc[i][j] = mfma16(aQl[i], bKh[j], acc[i][j]);
                acc[i][j] = mfma16(aQh[i], bKl[j], acc[i][j]);
            }
    }
    const float scale = 1.0f / sqrtf((float)*dkp);
#pragma unroll
    for (int i = 0; i < 2; i++)
#pragma unroll
        for (int j = 0; j < 2; j++)
#pragma unroll
            for (int r = 0; r < 4; r++) {
                const int qq = q0 + i * 16 + lk * 4 + r;
                const int kk = k0c + j * 16 + lr;
                const float v = (kk > qq) ? -INFINITY : acc[i][j][r] * scale;
                S[(size_t)qq * Tc + kk] = f16bits(v);
            }
}

// ---------------------------------------------------------------------------
// softmax_k: one block per row q.  Reads f16 logits, writes bf16 P in place
// (same bytes; each thread owns its 16B).  k>q forced to -inf (tiles there
// were never written).  P[k>q] = 0 so PV can run full tiles.
// ---------------------------------------------------------------------------
__global__ __launch_bounds__(256) void softmax_k(unsigned short* __restrict__ S) {
    const int q = blockIdx.x;
    const int tid = threadIdx.x;
    const int c0 = tid * 8;
    unsigned short* row = S + (size_t)q * Tc;

    uint4 raw = *reinterpret_cast<const uint4*>(row + c0);
    unsigned u[4] = {raw.x, raw.y, raw.z, raw.w};
    float v[8];
#pragma unroll
    for (int p = 0; p < 4; p++) {
        v[2 * p]     = f16val((unsigned short)(u[p] & 0xFFFFu));
        v[2 * p + 1] = f16val((unsigned short)(u[p] >> 16));
    }
#pragma unroll
    for (int i = 0; i < 8; i++)
        if (c0 + i > q) v[i] = -INFINITY;

    float m = v[0];
#pragma unroll
    for (int i = 1; i < 8; i++) m = fmaxf(m, v[i]);
#pragma unroll
    for (int off = 1; off < 64; off <<= 1) m = fmaxf(m, __shfl_xor(m, off));
    __shared__ float red[4];
    if ((tid & 63) == 0) red[tid >> 6] = m;
    __syncthreads();
    m = fmaxf(fmaxf(red[0], red[1]), fmaxf(red[2], red[3]));

    float e[8], s = 0.f;
#pragma unroll
    for (int i = 0; i < 8; i++) {
        e[i] = __expf(v[i] - m);  // exp(-inf)=0
        s += e[i];
    }
#pragma unroll
    for (int off = 1; off < 64; off <<= 1) s += __shfl_xor(s, off);
    __syncthreads();
    if ((tid & 63) == 0) red[tid >> 6] = s;
    __syncthreads();
    s = red[0] + red[1] + red[2] + red[3];
    const float inv = 1.0f / s;

    unsigned o[4];
#pragma unroll
    for (int p = 0; p < 4; p++) {
        unsigned short a = bf16bits(e[2 * p] * inv);
        unsigned short bb = bf16bits(e[2 * p + 1] * inv);
        o[p] = (unsigned)a | ((unsigned)bb << 16);
    }
    uint4 w; w.x = o[0]; w.y = o[1]; w.z = o[2]; w.w = o[3];
    *reinterpret_cast<uint4*>(row + c0) = w;
}

// ---------------------------------------------------------------------------
// pv_k: out[q][dout] = sum_k P[q][k] * V[k][dout] for one batch.
// A = P (bf16 row-major), B = Vt[dout][k] (contiguous along k).
// One wave per 32x32 out tile; k-loop limited to causal extent (P beyond is 0).
// ---------------------------------------------------------------------------
__global__ __launch_bounds__(64) void pv_k(const __bf16* __restrict__ P,
                                           const __bf16* __restrict__ vt,
                                           float* __restrict__ out) {
    const int id = blockIdx.x, iq = blockIdx.y;
    const int lane = threadIdx.x, lr = lane & 15, lk = lane >> 4;
    const int q0 = iq * 32, d0 = id * 32;
    const int kmax = q0 + 32;
    f32x4 acc[2][2] = {};
    for (int k0 = 0; k0 < kmax; k0 += 32) {
        const int kf = k0 + lk * 8;
        bf16x8 a[2], bv[2];
#pragma unroll
        for (int i = 0; i < 2; i++) {
            a[i]  = *reinterpret_cast<const bf16x8*>(P + (size_t)(q0 + i * 16 + lr) * Tc + kf);
            bv[i] = *reinterpret_cast<const bf16x8*>(vt + (size_t)(d0 + i * 16 + lr) * Tc + kf);
        }
#pragma unroll
        for (int i = 0; i < 2; i++)
#pragma unroll
            for (int j = 0; j < 2; j++)
                acc[i][j] = mfma16(a[i], bv[j], acc[i][j]);
    }
#pragma unroll
    for (int i = 0; i < 2; i++)
#pragma unroll
        for (int j = 0; j < 2; j++)
#pragma unroll
            for (int r = 0; r < 4; r++) {
                const int qq = q0 + i * 16 + lk * 4 + r;
                const int dd = d0 + j * 16 + lr;
                out[(size_t)qq * Hc + dd] = acc[i][j][r];
            }
}

// ---------------------------------------------------------------------------
extern "C" void kernel_launch(void* const* d_in, const int* in_sizes, int n_in,
                              void* d_out, int out_size, void* d_ws, size_t ws_size,
                              hipStream_t stream) {
    const float* x  = (const float*)d_in[0];
    const float* Wq = (const float*)d_in[1];
    const float* Wk = (const float*)d_in[2];
    const float* Wv = (const float*)d_in[3];
    const int*   dk = (const int*)d_in[4];
    float* out = (float*)d_out;
    char* ws = (char*)d_ws;

    const size_t SZ_XE = (size_t)Mc * Ec * 2;  // 32 MiB (bf16 [16384][1024])
    const size_t SZ_W  = (size_t)Ec * Hc * 2;  // 2 MiB

    size_t o = 0;
    auto nxt = [&](size_t bytes) { void* p = ws + o; o += bytes; return p; };
    __bf16* Xh   = (__bf16*)nxt(SZ_XE);
    __bf16* Xl   = (__bf16*)nxt(SZ_XE);
    __bf16* WqhT = (__bf16*)nxt(SZ_W);
    __bf16* WqlT = (__bf16*)nxt(SZ_W);
    __bf16* WkhT = (__bf16*)nxt(SZ_W);
    __bf16* WklT = (__bf16*)nxt(SZ_W);
    __bf16* WvhT = (__bf16*)nxt(SZ_W);
    __bf16* Qh   = (__bf16*)nxt(SZ_XE);
    __bf16* Ql   = (__bf16*)nxt(SZ_XE);
    __bf16* Kh   = (__bf16*)nxt(SZ_XE);
    __bf16* Kl   = (__bf16*)nxt(SZ_XE);
    __bf16* Vt   = (__bf16*)nxt(SZ_XE);
    // S (per-batch f16 [2048][2048], 8 MiB) aliases Xh — Xh is dead after the
    // three gemm_xw launches, and prep_x fully rewrites it next call.
    unsigned short* S = (unsigned short*)Xh;
    (void)ws_size; (void)in_sizes; (void)n_in; (void)out_size;

    prep_x<<<(Mc * Ec / 4 + 255) / 256, 256, 0, stream>>>(x, Xh, Xl, Mc * Ec);
    prep_w<<<dim3(32, 32, 3), 256, 0, stream>>>(Wq, Wk, Wv, WqhT, WqlT, WkhT, WklT, WvhT);

    gemm_xw<0><<<dim3(Hc / 32, Mc / 128), 256, 0, stream>>>(Xh, Xl, WqhT, WqlT, Qh, Ql);
    gemm_xw<0><<<dim3(Hc / 32, Mc / 128), 256, 0, stream>>>(Xh, Xl, WkhT, WklT, Kh, Kl);
    gemm_xw<1><<<dim3(Hc / 32, Mc / 128), 256, 0, stream>>>(Xh, nullptr, WvhT, nullptr, Vt, nullptr);

    for (int b = 0; b < Bc; b++) {
        energy_k<<<dim3(64, 64), 64, 0, stream>>>(Qh, Ql, Kh, Kl, S, dk, b);
        softmax_k<<<Tc, 256, 0, stream>>>(S);
        pv_k<<<dim3(Hc / 32, Tc / 32), 64, 0, stream>>>((const __bf16*)S,
                                                        Vt + (size_t)b * Hc * Tc,
                                                        out + (size_t)b * Tc * Hc);
    }
}

// Round 2
// 573.045 us; speedup vs baseline: 4.2106x; 4.2106x over previous
//
#include <hip/hip_runtime.h>

#define DEV __device__ __forceinline__

using f32x4  = __attribute__((ext_vector_type(4))) float;
using bf16x8 = __attribute__((ext_vector_type(8))) __bf16;
using bf16x4 = __attribute__((ext_vector_type(4))) __bf16;

constexpr int Bc = 8, Tc = 2048, Ec = 1024, Hc = 1024;
constexpr int Mc = Bc * Tc;  // 16384 total rows

DEV f32x4 mfma16(bf16x8 a, bf16x8 b, f32x4 c) {
    return __builtin_amdgcn_mfma_f32_16x16x32_bf16(a, b, c, 0, 0, 0);
}
DEV unsigned short f16bits(float f) { return __builtin_bit_cast(unsigned short, (_Float16)f); }
DEV float f16val(unsigned short u) { return (float)__builtin_bit_cast(_Float16, u); }
DEV unsigned short bf16bits(float f) { return __builtin_bit_cast(unsigned short, (__bf16)f); }

// async global->LDS, 16B per lane. LDS dest must be wave-uniform base; HW adds lane*16.
DEV void gload16(const __bf16* g, __bf16* l) {
    __builtin_amdgcn_global_load_lds(
        (const __attribute__((address_space(1))) unsigned int*)g,
        (__attribute__((address_space(3))) unsigned int*)l, 16, 0, 0);
}

// ---------------------------------------------------------------------------
// prep_x: split f32 x into hi/lo bf16 (x = hi + lo to ~17 mantissa bits)
// ---------------------------------------------------------------------------
__global__ __launch_bounds__(256) void prep_x(const float* __restrict__ x,
                                              __bf16* __restrict__ xh,
                                              __bf16* __restrict__ xl, int n) {
    int i = (blockIdx.x * 256 + threadIdx.x) * 4;
    if (i >= n) return;
    f32x4 v = *reinterpret_cast<const f32x4*>(x + i);
    bf16x4 h, l;
#pragma unroll
    for (int j = 0; j < 4; j++) {
        __bf16 hv = (__bf16)v[j];
        h[j] = hv;
        l[j] = (__bf16)(v[j] - (float)hv);
    }
    *reinterpret_cast<bf16x4*>(xh + i) = h;
    *reinterpret_cast<bf16x4*>(xl + i) = l;
}

// ---------------------------------------------------------------------------
// prep_w: transpose W[e][n] -> WT[n][e] and split hi/lo bf16 (V: hi only).
// ---------------------------------------------------------------------------
__global__ __launch_bounds__(256) void prep_w(const float* __restrict__ wq,
                                              const float* __restrict__ wk,
                                              const float* __restrict__ wv,
                                              __bf16* __restrict__ qh, __bf16* __restrict__ ql,
                                              __bf16* __restrict__ kh, __bf16* __restrict__ kl,
                                              __bf16* __restrict__ vh) {
    __shared__ float tile[32][33];
    const int z = blockIdx.z;
    const float* src = (z == 0) ? wq : (z == 1) ? wk : wv;
    __bf16* dh = (z == 0) ? qh : (z == 1) ? kh : vh;
    __bf16* dl = (z == 0) ? ql : (z == 1) ? kl : nullptr;
    const int n0 = blockIdx.x * 32, e0 = blockIdx.y * 32;
    const int tx = threadIdx.x & 31, ty = threadIdx.x >> 5;  // 32 x 8
#pragma unroll
    for (int j = 0; j < 32; j += 8)
        tile[ty + j][tx] = src[(size_t)(e0 + ty + j) * Hc + n0 + tx];
    __syncthreads();
#pragma unroll
    for (int j = 0; j < 32; j += 8) {
        float v = tile[tx][ty + j];
        __bf16 h = (__bf16)v;
        size_t idx = (size_t)(n0 + ty + j) * Ec + e0 + tx;
        dh[idx] = h;
        if (dl) dl[idx] = (__bf16)(v - (float)h);
    }
}

// ---------------------------------------------------------------------------
// gemm_tile: m97-structure 128x128 tile, BK=32, 4 waves (each 64x64 = 4x4
// MFMA frags), single LDS buffer, 2 barriers/K-step, global_load_lds staging.
// A [.][LDA], B [.][LDB] both K-contiguous. NTERMS==3 adds AlBh + AhBl.
// EPI: 0 = bf16 hi/lo row-major (Q/K proj, ld=Hc)
//      1 = bf16 transposed store Vt[b][n][t] (V proj)
//      2 = f16 causal energy * 1/sqrt(dk) (ld=Tc), tile-skip bx>by
//      3 = f32 row-major (PV, ld=Hc), kmax=(by+1)*128
// ---------------------------------------------------------------------------
template <int NTERMS, int EPI, int LDA, int LDB>
__global__ __launch_bounds__(256, 2) void gemm_tile(
        const __bf16* __restrict__ Ah, const __bf16* __restrict__ Al,
        const __bf16* __restrict__ Bh, const __bf16* __restrict__ Bl,
        void* __restrict__ out0, void* __restrict__ out1,
        const int* __restrict__ dkp,
        size_t aBS, size_t bBS, size_t oBS, int swz) {
    constexpr int NA = (NTERMS == 3) ? 2 : 1;
    __shared__ __bf16 sA[NA][128 * 32];
    __shared__ __bf16 sB[NA][128 * 32];

    int bx = blockIdx.x, by = blockIdx.y;
    if (swz) {  // bijective XCD chunking for grid (8, 128): XCD x owns m-tiles [16x,16x+16)
        const int lin = by * 8 + bx;
        by = (lin & 7) * 16 + (lin >> 6);
        bx = (lin >> 3) & 7;
    }
    if (EPI == 2 && bx > by) return;  // upper-triangle energy tiles: softmax masks them

    const int z = blockIdx.z;
    Ah += (size_t)z * aBS;
    Bh += (size_t)z * bBS;
    if (NTERMS == 3) { Al += (size_t)z * aBS; Bl += (size_t)z * bBS; }

    const int tid = threadIdx.x;
    const int wave = tid >> 6, lane = tid & 63;
    const int lr = lane & 15, lk = lane >> 4;
    const int wm = wave >> 1, wn = wave & 1;
    const int m0 = by * 128, n0 = bx * 128;

    // staging: inst i covers rows [i*64+wave*16, +16); lane -> row i*64+wave*16+lane/4,
    // k-chunk (lane&3)*8.  LDS linear: byte off = i*4096 + wave*1024 + lane*16.
    const int srow = wave * 16 + (lane >> 2);
    const int skc = (lane & 3) * 8;
    const int sdst = wave * 512;  // elements; + i*2048

    const int kmax = (EPI == 3) ? (by + 1) * 128 : Ec;

    f32x4 acc[4][4] = {};

    for (int k0 = 0; k0 < kmax; k0 += 32) {
#pragma unroll
        for (int i = 0; i < 2; i++) {
            const size_t goa = (size_t)(m0 + i * 64 + srow) * LDA + k0 + skc;
            const size_t gob = (size_t)(n0 + i * 64 + srow) * LDB + k0 + skc;
            __bf16* la = &sA[0][i * 2048 + sdst];
            __bf16* lb = &sB[0][i * 2048 + sdst];
            gload16(Ah + goa, la);
            gload16(Bh + gob, lb);
            if (NTERMS == 3) {
                gload16(Al + goa, &sA[NA - 1][i * 2048 + sdst]);
                gload16(Bl + gob, &sB[NA - 1][i * 2048 + sdst]);
            }
        }
        __syncthreads();  // compiler drains vmcnt(0) before s_barrier

        bf16x8 a_h[4], a_l[4], b_h[4], b_l[4];
#pragma unroll
        for (int i = 0; i < 4; i++) {
            const int ar = wm * 64 + i * 16 + lr;
            const int br = wn * 64 + i * 16 + lr;
            a_h[i] = *reinterpret_cast<const bf16x8*>(&sA[0][ar * 32 + lk * 8]);
            b_h[i] = *reinterpret_cast<const bf16x8*>(&sB[0][br * 32 + lk * 8]);
            if (NTERMS == 3) {
                a_l[i] = *reinterpret_cast<const bf16x8*>(&sA[NA - 1][ar * 32 + lk * 8]);
                b_l[i] = *reinterpret_cast<const bf16x8*>(&sB[NA - 1][br * 32 + lk * 8]);
            }
        }
#pragma unroll
        for (int i = 0; i < 4; i++)
#pragma unroll
            for (int j = 0; j < 4; j++) {
                acc[i][j] = mfma16(a_h[i], b_h[j], acc[i][j]);
                if (NTERMS == 3) {
                    acc[i][j] = mfma16(a_l[i], b_h[j], acc[i][j]);
                    acc[i][j] = mfma16(a_h[i], b_l[j], acc[i][j]);
                }
            }
        __syncthreads();  // all ds_reads done before next stage overwrites
    }

    float scale = 1.0f;
    if (EPI == 2) scale = 1.0f / sqrtf((float)*dkp);

#pragma unroll
    for (int i = 0; i < 4; i++)
#pragma unroll
        for (int j = 0; j < 4; j++)
#pragma unroll
            for (int r = 0; r < 4; r++) {
                const int gm = m0 + wm * 64 + i * 16 + lk * 4 + r;  // row=(lane>>4)*4+reg
                const int gn = n0 + wn * 64 + j * 16 + lr;          // col=lane&15
                const float v = acc[i][j][r];
                if (EPI == 0) {
                    __bf16 h = (__bf16)v;
                    ((__bf16*)out0)[(size_t)gm * Hc + gn] = h;
                    ((__bf16*)out1)[(size_t)gm * Hc + gn] = (__bf16)(v - (float)h);
                } else if (EPI == 1) {
                    const int bb = gm >> 11, t = gm & (Tc - 1);
                    ((__bf16*)out0)[((size_t)bb * Hc + gn) * Tc + t] = (__bf16)v;
                } else if (EPI == 2) {
                    const float e = (gn > gm) ? -INFINITY : v * scale;
                    ((unsigned short*)out0)[z * oBS + (size_t)gm * Tc + gn] = f16bits(e);
                } else {
                    ((float*)out0)[z * oBS + (size_t)gm * Hc + gn] = v;
                }
            }
}

// ---------------------------------------------------------------------------
// softmax_k: one block per (b,q) row.  Reads f16 logits, writes bf16 P in
// place.  k>q forced to -inf (covers never-written upper tiles); P[k>q]=0.
// ---------------------------------------------------------------------------
__global__ __launch_bounds__(256) void softmax_k(unsigned short* __restrict__ S) {
    const int q = blockIdx.x & (Tc - 1);
    const int b = blockIdx.x >> 11;
    const int tid = threadIdx.x;
    const int c0 = tid * 8;
    unsigned short* row = S + ((size_t)b * Tc + q) * Tc;

    uint4 raw = *reinterpret_cast<const uint4*>(row + c0);
    unsigned u[4] = {raw.x, raw.y, raw.z, raw.w};
    float v[8];
#pragma unroll
    for (int p = 0; p < 4; p++) {
        v[2 * p]     = f16val((unsigned short)(u[p] & 0xFFFFu));
        v[2 * p + 1] = f16val((unsigned short)(u[p] >> 16));
    }
#pragma unroll
    for (int i = 0; i < 8; i++)
        if (c0 + i > q) v[i] = -INFINITY;

    float m = v[0];
#pragma unroll
    for (int i = 1; i < 8; i++) m = fmaxf(m, v[i]);
#pragma unroll
    for (int off = 1; off < 64; off <<= 1) m = fmaxf(m, __shfl_xor(m, off));
    __shared__ float red[4];
    if ((tid & 63) == 0) red[tid >> 6] = m;
    __syncthreads();
    m = fmaxf(fmaxf(red[0], red[1]), fmaxf(red[2], red[3]));

    float e[8], s = 0.f;
#pragma unroll
    for (int i = 0; i < 8; i++) {
        e[i] = __expf(v[i] - m);  // exp(-inf)=0
        s += e[i];
    }
#pragma unroll
    for (int off = 1; off < 64; off <<= 1) s += __shfl_xor(s, off);
    __syncthreads();
    if ((tid & 63) == 0) red[tid >> 6] = s;
    __syncthreads();
    s = red[0] + red[1] + red[2] + red[3];
    const float inv = 1.0f / s;

    unsigned o[4];
#pragma unroll
    for (int p = 0; p < 4; p++) {
        unsigned short a = bf16bits(e[2 * p] * inv);
        unsigned short bb = bf16bits(e[2 * p + 1] * inv);
        o[p] = (unsigned)a | ((unsigned)bb << 16);
    }
    uint4 w; w.x = o[0]; w.y = o[1]; w.z = o[2]; w.w = o[3];
    *reinterpret_cast<uint4*>(row + c0) = w;
}

// ---------------------------------------------------------------------------
extern "C" void kernel_launch(void* const* d_in, const int* in_sizes, int n_in,
                              void* d_out, int out_size, void* d_ws, size_t ws_size,
                              hipStream_t stream) {
    const float* x  = (const float*)d_in[0];
    const float* Wq = (const float*)d_in[1];
    const float* Wk = (const float*)d_in[2];
    const float* Wv = (const float*)d_in[3];
    const int*   dk = (const int*)d_in[4];
    float* out = (float*)d_out;
    char* ws = (char*)d_ws;

    const size_t SZ_XE = (size_t)Mc * Ec * 2;  // 32 MiB
    const size_t SZ_W  = (size_t)Ec * Hc * 2;  // 2 MiB

    size_t o = 0;
    auto nxt = [&](size_t bytes) { void* p = ws + o; o += bytes; return p; };
    __bf16* Xh   = (__bf16*)nxt(SZ_XE);
    __bf16* Xl   = (__bf16*)nxt(SZ_XE);
    __bf16* WqhT = (__bf16*)nxt(SZ_W);
    __bf16* WqlT = (__bf16*)nxt(SZ_W);
    __bf16* WkhT = (__bf16*)nxt(SZ_W);
    __bf16* WklT = (__bf16*)nxt(SZ_W);
    __bf16* WvhT = (__bf16*)nxt(SZ_W);
    __bf16* Qh   = (__bf16*)nxt(SZ_XE);
    __bf16* Ql   = (__bf16*)nxt(SZ_XE);
    __bf16* Kh   = (__bf16*)nxt(SZ_XE);
    __bf16* Kl   = (__bf16*)nxt(SZ_XE);
    __bf16* Vt   = (__bf16*)nxt(SZ_XE);
    // S: all-batch f16 [8][2048][2048] = 64 MiB, aliases Xh+Xl (dead after projections)
    unsigned short* S = (unsigned short*)Xh;
    (void)ws_size; (void)in_sizes; (void)n_in; (void)out_size;

    prep_x<<<(Mc * Ec / 4 + 255) / 256, 256, 0, stream>>>(x, Xh, Xl, Mc * Ec);
    prep_w<<<dim3(32, 32, 3), 256, 0, stream>>>(Wq, Wk, Wv, WqhT, WqlT, WkhT, WklT, WvhT);

    // Q/K projections: 3-term split, bf16 hi/lo out
    gemm_tile<3, 0, Ec, Ec><<<dim3(8, Mc / 128, 1), 256, 0, stream>>>(
        Xh, Xl, WqhT, WqlT, Qh, Ql, dk, 0, 0, 0, 1);
    gemm_tile<3, 0, Ec, Ec><<<dim3(8, Mc / 128, 1), 256, 0, stream>>>(
        Xh, Xl, WkhT, WklT, Kh, Kl, dk, 0, 0, 0, 1);
    // V projection: 1-term, transposed store Vt[b][dout][t]
    gemm_tile<1, 1, Ec, Ec><<<dim3(8, Mc / 128, 1), 256, 0, stream>>>(
        Xh, nullptr, WvhT, nullptr, Vt, nullptr, dk, 0, 0, 0, 1);

    // energy: all batches, causal tiles only, f16 logits
    gemm_tile<3, 2, Hc, Hc><<<dim3(16, 16, Bc), 256, 0, stream>>>(
        Qh, Ql, Kh, Kl, S, nullptr, dk,
        (size_t)Tc * Hc, (size_t)Tc * Hc, (size_t)Tc * Tc, 0);

    softmax_k<<<Bc * Tc, 256, 0, stream>>>(S);

    // PV: all batches, kmax=(by+1)*128 (P beyond causal edge is 0)
    gemm_tile<1, 3, Tc, Tc><<<dim3(8, 16, Bc), 256, 0, stream>>>(
        (const __bf16*)S, nullptr, Vt, nullptr, out, nullptr, dk,
        (size_t)Tc * Tc, (size_t)Hc * Tc, (size_t)Tc * Hc, 0);
}

// Round 3
// 564.416 us; speedup vs baseline: 4.2750x; 1.0153x over previous
//
#include <hip/hip_runtime.h>

#define DEV __device__ __forceinline__

using f32x4  = __attribute__((ext_vector_type(4))) float;
using bf16x8 = __attribute__((ext_vector_type(8))) __bf16;
using bf16x4 = __attribute__((ext_vector_type(4))) __bf16;

constexpr int Bc = 8, Tc = 2048, Ec = 1024, Hc = 1024;
constexpr int Mc = Bc * Tc;  // 16384 total rows

DEV f32x4 mfma16(bf16x8 a, bf16x8 b, f32x4 c) {
    return __builtin_amdgcn_mfma_f32_16x16x32_bf16(a, b, c, 0, 0, 0);
}
DEV unsigned short f16bits(float f) { return __builtin_bit_cast(unsigned short, (_Float16)f); }
DEV float f16val(unsigned short u) { return (float)__builtin_bit_cast(_Float16, u); }
DEV unsigned short bf16bits(float f) { return __builtin_bit_cast(unsigned short, (__bf16)f); }

// async global->LDS, 16B per lane. LDS dest must be wave-uniform base; HW adds lane*16.
DEV void gload16(const __bf16* g, __bf16* l) {
    __builtin_amdgcn_global_load_lds(
        (const __attribute__((address_space(1))) unsigned int*)g,
        (__attribute__((address_space(3))) unsigned int*)l, 16, 0, 0);
}

// ---------------------------------------------------------------------------
// prep_x: split f32 x into hi/lo bf16 (x = hi + lo to ~17 mantissa bits)
// ---------------------------------------------------------------------------
__global__ __launch_bounds__(256) void prep_x(const float* __restrict__ x,
                                              __bf16* __restrict__ xh,
                                              __bf16* __restrict__ xl, int n) {
    int i = (blockIdx.x * 256 + threadIdx.x) * 4;
    if (i >= n) return;
    f32x4 v = *reinterpret_cast<const f32x4*>(x + i);
    bf16x4 h, l;
#pragma unroll
    for (int j = 0; j < 4; j++) {
        __bf16 hv = (__bf16)v[j];
        h[j] = hv;
        l[j] = (__bf16)(v[j] - (float)hv);
    }
    *reinterpret_cast<bf16x4*>(xh + i) = h;
    *reinterpret_cast<bf16x4*>(xl + i) = l;
}

// ---------------------------------------------------------------------------
// prep_w: transpose W[e][n] -> WT[n][e] and split hi/lo bf16 (V: hi only).
// ---------------------------------------------------------------------------
__global__ __launch_bounds__(256) void prep_w(const float* __restrict__ wq,
                                              const float* __restrict__ wk,
                                              const float* __restrict__ wv,
                                              __bf16* __restrict__ qh, __bf16* __restrict__ ql,
                                              __bf16* __restrict__ kh, __bf16* __restrict__ kl,
                                              __bf16* __restrict__ vh) {
    __shared__ float tile[32][33];
    const int z = blockIdx.z;
    const float* src = (z == 0) ? wq : (z == 1) ? wk : wv;
    __bf16* dh = (z == 0) ? qh : (z == 1) ? kh : vh;
    __bf16* dl = (z == 0) ? ql : (z == 1) ? kl : nullptr;
    const int n0 = blockIdx.x * 32, e0 = blockIdx.y * 32;
    const int tx = threadIdx.x & 31, ty = threadIdx.x >> 5;  // 32 x 8
#pragma unroll
    for (int j = 0; j < 32; j += 8)
        tile[ty + j][tx] = src[(size_t)(e0 + ty + j) * Hc + n0 + tx];
    __syncthreads();
#pragma unroll
    for (int j = 0; j < 32; j += 8) {
        float v = tile[tx][ty + j];
        __bf16 h = (__bf16)v;
        size_t idx = (size_t)(n0 + ty + j) * Ec + e0 + tx;
        dh[idx] = h;
        if (dl) dl[idx] = (__bf16)(v - (float)h);
    }
}

// ---------------------------------------------------------------------------
// gemm_tile: 128x128 tile, BK=32, 4 waves (each 64x64 = 4x4 MFMA frags),
// DOUBLE-buffered LDS with T3-minimum prefetch: issue next K-step's
// global_load_lds before ds_read+MFMA of current step; ONE __syncthreads per
// K-step (emits the vmcnt(0)+lgkmcnt(0)+s_barrier drain).
// A [.][LDA], B [.][LDB] both K-contiguous. NTERMS==3 adds AlBh + AhBl.
// EPI: 0 = bf16 hi/lo row-major (Q/K proj, ld=Hc)
//      1 = bf16 transposed store Vt[b][n][t] (V proj)
//      2 = f16 causal energy * 1/sqrt(dk) (ld=Tc), tile-skip bx>by
//      3 = f32 row-major (PV, ld=Hc), kmax=(by+1)*128
// ---------------------------------------------------------------------------
template <int NTERMS, int EPI, int LDA, int LDB>
__global__ __launch_bounds__(256, 2) void gemm_tile(
        const __bf16* __restrict__ Ah, const __bf16* __restrict__ Al,
        const __bf16* __restrict__ Bh, const __bf16* __restrict__ Bl,
        void* __restrict__ out0, void* __restrict__ out1,
        const int* __restrict__ dkp,
        size_t aBS, size_t bBS, size_t oBS, int swz) {
    constexpr int NA = (NTERMS == 3) ? 2 : 1;
    __shared__ __bf16 sA[2][NA][128 * 32];
    __shared__ __bf16 sB[2][NA][128 * 32];

    int bx = blockIdx.x, by = blockIdx.y;
    if (swz) {  // bijective XCD chunking for grid (8, 128): XCD x owns m-tiles [16x,16x+16)
        const int lin = by * 8 + bx;
        by = (lin & 7) * 16 + (lin >> 6);
        bx = (lin >> 3) & 7;
    }
    if (EPI == 2 && bx > by) return;  // upper-triangle energy tiles: softmax masks them

    const int z = blockIdx.z;
    Ah += (size_t)z * aBS;
    Bh += (size_t)z * bBS;
    if (NTERMS == 3) { Al += (size_t)z * aBS; Bl += (size_t)z * bBS; }

    const int tid = threadIdx.x;
    const int wave = tid >> 6, lane = tid & 63;
    const int lr = lane & 15, lk = lane >> 4;
    const int wm = wave >> 1, wn = wave & 1;
    const int m0 = by * 128, n0 = bx * 128;

    // staging: inst i covers rows [i*64+wave*16, +16); lane -> row i*64+wave*16+lane/4,
    // k-chunk (lane&3)*8.  LDS linear per buf/term: elem off = i*2048 + wave*512 + lane*8.
    const int srow = wave * 16 + (lane >> 2);
    const int skc = (lane & 3) * 8;
    const int sdst = wave * 512;  // elements; + i*2048

    const int kmax = (EPI == 3) ? (by + 1) * 128 : Ec;

    auto STAGE = [&](int buf, int k0) {
#pragma unroll
        for (int i = 0; i < 2; i++) {
            const size_t goa = (size_t)(m0 + i * 64 + srow) * LDA + k0 + skc;
            const size_t gob = (size_t)(n0 + i * 64 + srow) * LDB + k0 + skc;
            gload16(Ah + goa, &sA[buf][0][i * 2048 + sdst]);
            gload16(Bh + gob, &sB[buf][0][i * 2048 + sdst]);
            if (NTERMS == 3) {
                gload16(Al + goa, &sA[buf][NA - 1][i * 2048 + sdst]);
                gload16(Bl + gob, &sB[buf][NA - 1][i * 2048 + sdst]);
            }
        }
    };

    f32x4 acc[4][4] = {};

    STAGE(0, 0);
    __syncthreads();  // drain prologue stage (vmcnt(0) + barrier)
    int cur = 0;

    for (int k0 = 0; k0 < kmax; k0 += 32) {
        if (k0 + 32 < kmax) STAGE(cur ^ 1, k0 + 32);  // prefetch next K-step

        bf16x8 a_h[4], a_l[4], b_h[4], b_l[4];
#pragma unroll
        for (int i = 0; i < 4; i++) {
            const int ar = wm * 64 + i * 16 + lr;
            const int br = wn * 64 + i * 16 + lr;
            a_h[i] = *reinterpret_cast<const bf16x8*>(&sA[cur][0][ar * 32 + lk * 8]);
            b_h[i] = *reinterpret_cast<const bf16x8*>(&sB[cur][0][br * 32 + lk * 8]);
            if (NTERMS == 3) {
                a_l[i] = *reinterpret_cast<const bf16x8*>(&sA[cur][NA - 1][ar * 32 + lk * 8]);
                b_l[i] = *reinterpret_cast<const bf16x8*>(&sB[cur][NA - 1][br * 32 + lk * 8]);
            }
        }
#pragma unroll
        for (int i = 0; i < 4; i++)
#pragma unroll
            for (int j = 0; j < 4; j++) {
                acc[i][j] = mfma16(a_h[i], b_h[j], acc[i][j]);
                if (NTERMS == 3) {
                    acc[i][j] = mfma16(a_l[i], b_h[j], acc[i][j]);
                    acc[i][j] = mfma16(a_h[i], b_l[j], acc[i][j]);
                }
            }
        __syncthreads();  // drains prefetch (vmcnt0) + protects buf reuse
        cur ^= 1;
    }

    float scale = 1.0f;
    if (EPI == 2) scale = 1.0f / sqrtf((float)*dkp);

#pragma unroll
    for (int i = 0; i < 4; i++)
#pragma unroll
        for (int j = 0; j < 4; j++)
#pragma unroll
            for (int r = 0; r < 4; r++) {
                const int gm = m0 + wm * 64 + i * 16 + lk * 4 + r;  // row=(lane>>4)*4+reg
                const int gn = n0 + wn * 64 + j * 16 + lr;          // col=lane&15
                const float v = acc[i][j][r];
                if (EPI == 0) {
                    __bf16 h = (__bf16)v;
                    ((__bf16*)out0)[(size_t)gm * Hc + gn] = h;
                    ((__bf16*)out1)[(size_t)gm * Hc + gn] = (__bf16)(v - (float)h);
                } else if (EPI == 1) {
                    const int bb = gm >> 11, t = gm & (Tc - 1);
                    ((__bf16*)out0)[((size_t)bb * Hc + gn) * Tc + t] = (__bf16)v;
                } else if (EPI == 2) {
                    const float e = (gn > gm) ? -INFINITY : v * scale;
                    ((unsigned short*)out0)[z * oBS + (size_t)gm * Tc + gn] = f16bits(e);
                } else {
                    ((float*)out0)[z * oBS + (size_t)gm * Hc + gn] = v;
                }
            }
}

// ---------------------------------------------------------------------------
// softmax_k: one block per (b,q) row.  Reads f16 logits, writes bf16 P in
// place.  k>q forced to -inf (covers never-written upper tiles); P[k>q]=0.
// ---------------------------------------------------------------------------
__global__ __launch_bounds__(256) void softmax_k(unsigned short* __restrict__ S) {
    const int q = blockIdx.x & (Tc - 1);
    const int b = blockIdx.x >> 11;
    const int tid = threadIdx.x;
    const int c0 = tid * 8;
    unsigned short* row = S + ((size_t)b * Tc + q) * Tc;

    uint4 raw = *reinterpret_cast<const uint4*>(row + c0);
    unsigned u[4] = {raw.x, raw.y, raw.z, raw.w};
    float v[8];
#pragma unroll
    for (int p = 0; p < 4; p++) {
        v[2 * p]     = f16val((unsigned short)(u[p] & 0xFFFFu));
        v[2 * p + 1] = f16val((unsigned short)(u[p] >> 16));
    }
#pragma unroll
    for (int i = 0; i < 8; i++)
        if (c0 + i > q) v[i] = -INFINITY;

    float m = v[0];
#pragma unroll
    for (int i = 1; i < 8; i++) m = fmaxf(m, v[i]);
#pragma unroll
    for (int off = 1; off < 64; off <<= 1) m = fmaxf(m, __shfl_xor(m, off));
    __shared__ float red[4];
    if ((tid & 63) == 0) red[tid >> 6] = m;
    __syncthreads();
    m = fmaxf(fmaxf(red[0], red[1]), fmaxf(red[2], red[3]));

    float e[8], s = 0.f;
#pragma unroll
    for (int i = 0; i < 8; i++) {
        e[i] = __expf(v[i] - m);  // exp(-inf)=0
        s += e[i];
    }
#pragma unroll
    for (int off = 1; off < 64; off <<= 1) s += __shfl_xor(s, off);
    __syncthreads();
    if ((tid & 63) == 0) red[tid >> 6] = s;
    __syncthreads();
    s = red[0] + red[1] + red[2] + red[3];
    const float inv = 1.0f / s;

    unsigned o[4];
#pragma unroll
    for (int p = 0; p < 4; p++) {
        unsigned short a = bf16bits(e[2 * p] * inv);
        unsigned short bb = bf16bits(e[2 * p + 1] * inv);
        o[p] = (unsigned)a | ((unsigned)bb << 16);
    }
    uint4 w; w.x = o[0]; w.y = o[1]; w.z = o[2]; w.w = o[3];
    *reinterpret_cast<uint4*>(row + c0) = w;
}

// ---------------------------------------------------------------------------
extern "C" void kernel_launch(void* const* d_in, const int* in_sizes, int n_in,
                              void* d_out, int out_size, void* d_ws, size_t ws_size,
                              hipStream_t stream) {
    const float* x  = (const float*)d_in[0];
    const float* Wq = (const float*)d_in[1];
    const float* Wk = (const float*)d_in[2];
    const float* Wv = (const float*)d_in[3];
    const int*   dk = (const int*)d_in[4];
    float* out = (float*)d_out;
    char* ws = (char*)d_ws;

    const size_t SZ_XE = (size_t)Mc * Ec * 2;  // 32 MiB
    const size_t SZ_W  = (size_t)Ec * Hc * 2;  // 2 MiB

    size_t o = 0;
    auto nxt = [&](size_t bytes) { void* p = ws + o; o += bytes; return p; };
    __bf16* Xh   = (__bf16*)nxt(SZ_XE);
    __bf16* Xl   = (__bf16*)nxt(SZ_XE);
    __bf16* WqhT = (__bf16*)nxt(SZ_W);
    __bf16* WqlT = (__bf16*)nxt(SZ_W);
    __bf16* WkhT = (__bf16*)nxt(SZ_W);
    __bf16* WklT = (__bf16*)nxt(SZ_W);
    __bf16* WvhT = (__bf16*)nxt(SZ_W);
    __bf16* Qh   = (__bf16*)nxt(SZ_XE);
    __bf16* Ql   = (__bf16*)nxt(SZ_XE);
    __bf16* Kh   = (__bf16*)nxt(SZ_XE);
    __bf16* Kl   = (__bf16*)nxt(SZ_XE);
    __bf16* Vt   = (__bf16*)nxt(SZ_XE);
    // S: all-batch f16 [8][2048][2048] = 64 MiB, aliases Xh+Xl (dead after projections)
    unsigned short* S = (unsigned short*)Xh;
    (void)ws_size; (void)in_sizes; (void)n_in; (void)out_size;

    prep_x<<<(Mc * Ec / 4 + 255) / 256, 256, 0, stream>>>(x, Xh, Xl, Mc * Ec);
    prep_w<<<dim3(32, 32, 3), 256, 0, stream>>>(Wq, Wk, Wv, WqhT, WqlT, WkhT, WklT, WvhT);

    // Q/K projections: 3-term split, bf16 hi/lo out
    gemm_tile<3, 0, Ec, Ec><<<dim3(8, Mc / 128, 1), 256, 0, stream>>>(
        Xh, Xl, WqhT, WqlT, Qh, Ql, dk, 0, 0, 0, 1);
    gemm_tile<3, 0, Ec, Ec><<<dim3(8, Mc / 128, 1), 256, 0, stream>>>(
        Xh, Xl, WkhT, WklT, Kh, Kl, dk, 0, 0, 0, 1);
    // V projection: 1-term, transposed store Vt[b][dout][t]
    gemm_tile<1, 1, Ec, Ec><<<dim3(8, Mc / 128, 1), 256, 0, stream>>>(
        Xh, nullptr, WvhT, nullptr, Vt, nullptr, dk, 0, 0, 0, 1);

    // energy: all batches, causal tiles only, f16 logits
    gemm_tile<3, 2, Hc, Hc><<<dim3(16, 16, Bc), 256, 0, stream>>>(
        Qh, Ql, Kh, Kl, S, nullptr, dk,
        (size_t)Tc * Hc, (size_t)Tc * Hc, (size_t)Tc * Tc, 0);

    softmax_k<<<Bc * Tc, 256, 0, stream>>>(S);

    // PV: all batches, kmax=(by+1)*128 (P beyond causal edge is 0)
    gemm_tile<1, 3, Tc, Tc><<<dim3(8, 16, Bc), 256, 0, stream>>>(
        (const __bf16*)S, nullptr, Vt, nullptr, out, nullptr, dk,
        (size_t)Tc * Tc, (size_t)Hc * Tc, (size_t)Tc * Hc, 0);
}

// Round 4
// 541.241 us; speedup vs baseline: 4.4580x; 1.0428x over previous
//
#include <hip/hip_runtime.h>

#define DEV __device__ __forceinline__

using f32x4  = __attribute__((ext_vector_type(4))) float;
using bf16x8 = __attribute__((ext_vector_type(8))) __bf16;
using bf16x4 = __attribute__((ext_vector_type(4))) __bf16;

constexpr int Bc = 8, Tc = 2048, Ec = 1024, Hc = 1024;
constexpr int Mc = Bc * Tc;  // 16384 total rows

DEV f32x4 mfma16(bf16x8 a, bf16x8 b, f32x4 c) {
    return __builtin_amdgcn_mfma_f32_16x16x32_bf16(a, b, c, 0, 0, 0);
}
DEV unsigned short f16bits(float f) { return __builtin_bit_cast(unsigned short, (_Float16)f); }
DEV float f16val(unsigned short u) { return (float)__builtin_bit_cast(_Float16, u); }
DEV unsigned short bf16bits(float f) { return __builtin_bit_cast(unsigned short, (__bf16)f); }

// async global->LDS, 16B per lane. LDS dest must be wave-uniform base; HW adds lane*16.
DEV void gload16(const __bf16* g, __bf16* l) {
    __builtin_amdgcn_global_load_lds(
        (const __attribute__((address_space(1))) unsigned int*)g,
        (__attribute__((address_space(3))) unsigned int*)l, 16, 0, 0);
}

// ---------------------------------------------------------------------------
// prep_x: split f32 x into hi/lo bf16 (x = hi + lo to ~17 mantissa bits)
// ---------------------------------------------------------------------------
__global__ __launch_bounds__(256) void prep_x(const float* __restrict__ x,
                                              __bf16* __restrict__ xh,
                                              __bf16* __restrict__ xl, int n) {
    int i = (blockIdx.x * 256 + threadIdx.x) * 4;
    if (i >= n) return;
    f32x4 v = *reinterpret_cast<const f32x4*>(x + i);
    bf16x4 h, l;
#pragma unroll
    for (int j = 0; j < 4; j++) {
        __bf16 hv = (__bf16)v[j];
        h[j] = hv;
        l[j] = (__bf16)(v[j] - (float)hv);
    }
    *reinterpret_cast<bf16x4*>(xh + i) = h;
    *reinterpret_cast<bf16x4*>(xl + i) = l;
}

// ---------------------------------------------------------------------------
// prep_w: transpose W[e][n] -> WT[n][e] and split hi/lo bf16 (V: hi only).
// ---------------------------------------------------------------------------
__global__ __launch_bounds__(256) void prep_w(const float* __restrict__ wq,
                                              const float* __restrict__ wk,
                                              const float* __restrict__ wv,
                                              __bf16* __restrict__ qh, __bf16* __restrict__ ql,
                                              __bf16* __restrict__ kh, __bf16* __restrict__ kl,
                                              __bf16* __restrict__ vh) {
    __shared__ float tile[32][33];
    const int z = blockIdx.z;
    const float* src = (z == 0) ? wq : (z == 1) ? wk : wv;
    __bf16* dh = (z == 0) ? qh : (z == 1) ? kh : vh;
    __bf16* dl = (z == 0) ? ql : (z == 1) ? kl : nullptr;
    const int n0 = blockIdx.x * 32, e0 = blockIdx.y * 32;
    const int tx = threadIdx.x & 31, ty = threadIdx.x >> 5;  // 32 x 8
#pragma unroll
    for (int j = 0; j < 32; j += 8)
        tile[ty + j][tx] = src[(size_t)(e0 + ty + j) * Hc + n0 + tx];
    __syncthreads();
#pragma unroll
    for (int j = 0; j < 32; j += 8) {
        float v = tile[tx][ty + j];
        __bf16 h = (__bf16)v;
        size_t idx = (size_t)(n0 + ty + j) * Ec + e0 + tx;
        dh[idx] = h;
        if (dl) dl[idx] = (__bf16)(v - (float)h);
    }
}

// ---------------------------------------------------------------------------
// gemm8: 256x256 tile, 8 waves (2x4, each 128x64), 512 threads, BK-slice = 32.
// 4-slot LDS ring (A[256][32]+B[256][32] per slot = 32KB; 4 slots = 128KB).
// Phase P: {vmcnt(8); s_barrier; ds_read slice P (12xb128); stage slice P+3
// (4x global_load_lds); setprio(1); 32 MFMA; setprio(0)}.
// vmcnt counted (8 = 2 slices in flight allowed); never 0 until the tail.
// Race-freedom: stage at P targets slot (P-1)&3, whose readers passed P's
// barrier only after their lgkmcnt-complete ds_reads.
// NTERMS==3: virtual K = 3*1024 with per-slice source remap:
//   term0: Ah*Bh, term1: Al*Bh, term2: Ah*Bl  (= full hi/lo 3-term product).
// EPI: 0 = bf16 hi/lo row-major out (Q/K proj)
//      1 = bf16 transposed store Vt[b][n][t] (V proj)
//      2 = f16 causal energy * 1/sqrt(dk), tile-skip bx>by
//      3 = f32 row-major (PV), nkt = (by+1)*8
// ---------------------------------------------------------------------------
template <int NTERMS, int EPI>
__global__ __launch_bounds__(512, 2) void gemm8(
        const __bf16* __restrict__ Ah, const __bf16* __restrict__ Al,
        const __bf16* __restrict__ Bh, const __bf16* __restrict__ Bl,
        void* __restrict__ out0, void* __restrict__ out1,
        const int* __restrict__ dkp,
        int lda, int ldb, size_t aBS, size_t bBS, size_t oBS,
        int nkt, int swz) {
    __shared__ __bf16 sA[4][256 * 32];  // 64 KiB
    __shared__ __bf16 sB[4][256 * 32];  // 64 KiB

    int bx = blockIdx.x, by = blockIdx.y;
    if (swz) {  // bijective XCD chunking for grid (4,64): XCD x owns by in [8x, 8x+8)
        const int lin = by * 4 + bx;
        const int w = (lin & 7) * 32 + (lin >> 3);
        by = w >> 2;
        bx = w & 3;
    }
    if (EPI == 2 && bx > by) return;  // upper-triangle energy tiles: softmax masks them
    if (EPI == 3) nkt = (by + 1) * 8;  // causal K extent

    const int z = blockIdx.z;
    Ah += (size_t)z * aBS;
    Bh += (size_t)z * bBS;
    if (NTERMS == 3) { Al += (size_t)z * aBS; Bl += (size_t)z * bBS; }

    const int tid = threadIdx.x;
    const int wave = tid >> 6, lane = tid & 63;
    const int lr = lane & 15, lk = lane >> 4;
    const int wm = wave >> 2, wn = wave & 3;  // 2 x 4 wave grid
    const int m0 = by * 256, n0 = bx * 256;

    // staging: chunk c = (wave*2+l)*64 + lane covers slice linearly;
    // row = wave*32 + l*16 + lane/4, k-chunk = (lane&3)*8.
    const int arow = wave * 32 + (lane >> 2);
    const int akc = (lane & 3) * 8;

    auto stage = [&](int sv) {
        const int slot = sv & 3;
        const __bf16 *as, *bs;
        int kk;
        if (NTERMS == 3) {
            const int term = sv >> 5;
            kk = (sv & 31) * 32;
            as = (term == 1) ? Al : Ah;
            bs = (term == 2) ? Bl : Bh;
        } else {
            as = Ah;
            bs = Bh;
            kk = sv * 32;
        }
#pragma unroll
        for (int l = 0; l < 2; l++) {
            gload16(as + (size_t)(m0 + arow + l * 16) * lda + kk + akc,
                    &sA[slot][(wave * 2 + l) * 512]);
            gload16(bs + (size_t)(n0 + arow + l * 16) * ldb + kk + akc,
                    &sB[slot][(wave * 2 + l) * 512]);
        }
    };

    f32x4 acc[8][4] = {};

    // prologue: 3 slices in flight
    stage(0);
    stage(1);
    stage(2);

    for (int P = 0; P < nkt; ++P) {
        const int rem = nkt - 1 - P;
        if (rem >= 2)
            asm volatile("s_waitcnt vmcnt(8)" ::: "memory");
        else if (rem == 1)
            asm volatile("s_waitcnt vmcnt(4)" ::: "memory");
        else
            asm volatile("s_waitcnt vmcnt(0)" ::: "memory");
        __builtin_amdgcn_s_barrier();
        __builtin_amdgcn_sched_barrier(0);

        const int slot = P & 3;
        bf16x8 af[8], bfr[4];
#pragma unroll
        for (int mi = 0; mi < 8; mi++)
            af[mi] = *reinterpret_cast<const bf16x8*>(
                &sA[slot][(wm * 128 + mi * 16 + lr) * 32 + lk * 8]);
#pragma unroll
        for (int nj = 0; nj < 4; nj++)
            bfr[nj] = *reinterpret_cast<const bf16x8*>(
                &sB[slot][(wn * 64 + nj * 16 + lr) * 32 + lk * 8]);

        if (P + 3 < nkt) stage(P + 3);

        __builtin_amdgcn_s_setprio(1);
#pragma unroll
        for (int mi = 0; mi < 8; mi++)
#pragma unroll
            for (int nj = 0; nj < 4; nj++)
                acc[mi][nj] = mfma16(af[mi], bfr[nj], acc[mi][nj]);
        __builtin_amdgcn_s_setprio(0);
    }

    float scale = 1.0f;
    if (EPI == 2) scale = 1.0f / sqrtf((float)*dkp);

#pragma unroll
    for (int mi = 0; mi < 8; mi++)
#pragma unroll
        for (int nj = 0; nj < 4; nj++) {
            const int gn = n0 + wn * 64 + nj * 16 + lr;
            if (EPI == 1) {
                const int gm0 = m0 + wm * 128 + mi * 16 + lk * 4;
                const int bb = gm0 >> 11, t = gm0 & (Tc - 1);
                bf16x4 pk;
#pragma unroll
                for (int r = 0; r < 4; r++) pk[r] = (__bf16)acc[mi][nj][r];
                *reinterpret_cast<bf16x4*>(
                    &((__bf16*)out0)[((size_t)(bb * Hc + gn)) * Tc + t]) = pk;
            } else {
#pragma unroll
                for (int r = 0; r < 4; r++) {
                    const int gm = m0 + wm * 128 + mi * 16 + lk * 4 + r;
                    const float v = acc[mi][nj][r];
                    if (EPI == 0) {
                        __bf16 h = (__bf16)v;
                        ((__bf16*)out0)[(size_t)gm * Hc + gn] = h;
                        ((__bf16*)out1)[(size_t)gm * Hc + gn] = (__bf16)(v - (float)h);
                    } else if (EPI == 2) {
                        const float e = (gn > gm) ? -INFINITY : v * scale;
                        ((unsigned short*)out0)[(size_t)z * oBS + (size_t)gm * Tc + gn] =
                            f16bits(e);
                    } else {
                        ((float*)out0)[(size_t)z * oBS + (size_t)gm * Hc + gn] = v;
                    }
                }
            }
        }
}

// ---------------------------------------------------------------------------
// softmax_k: one block per (b,q) row.  Reads f16 logits, writes bf16 P in
// place.  k>q forced to -inf (covers never-written upper tiles); P[k>q]=0.
// ---------------------------------------------------------------------------
__global__ __launch_bounds__(256) void softmax_k(unsigned short* __restrict__ S) {
    const int q = blockIdx.x & (Tc - 1);
    const int b = blockIdx.x >> 11;
    const int tid = threadIdx.x;
    const int c0 = tid * 8;
    unsigned short* row = S + ((size_t)b * Tc + q) * Tc;

    uint4 raw = *reinterpret_cast<const uint4*>(row + c0);
    unsigned u[4] = {raw.x, raw.y, raw.z, raw.w};
    float v[8];
#pragma unroll
    for (int p = 0; p < 4; p++) {
        v[2 * p]     = f16val((unsigned short)(u[p] & 0xFFFFu));
        v[2 * p + 1] = f16val((unsigned short)(u[p] >> 16));
    }
#pragma unroll
    for (int i = 0; i < 8; i++)
        if (c0 + i > q) v[i] = -INFINITY;

    float m = v[0];
#pragma unroll
    for (int i = 1; i < 8; i++) m = fmaxf(m, v[i]);
#pragma unroll
    for (int off = 1; off < 64; off <<= 1) m = fmaxf(m, __shfl_xor(m, off));
    __shared__ float red[4];
    if ((tid & 63) == 0) red[tid >> 6] = m;
    __syncthreads();
    m = fmaxf(fmaxf(red[0], red[1]), fmaxf(red[2], red[3]));

    float e[8], s = 0.f;
#pragma unroll
    for (int i = 0; i < 8; i++) {
        e[i] = __expf(v[i] - m);  // exp(-inf)=0
        s += e[i];
    }
#pragma unroll
    for (int off = 1; off < 64; off <<= 1) s += __shfl_xor(s, off);
    __syncthreads();
    if ((tid & 63) == 0) red[tid >> 6] = s;
    __syncthreads();
    s = red[0] + red[1] + red[2] + red[3];
    const float inv = 1.0f / s;

    unsigned o[4];
#pragma unroll
    for (int p = 0; p < 4; p++) {
        unsigned short a = bf16bits(e[2 * p] * inv);
        unsigned short bb = bf16bits(e[2 * p + 1] * inv);
        o[p] = (unsigned)a | ((unsigned)bb << 16);
    }
    uint4 w; w.x = o[0]; w.y = o[1]; w.z = o[2]; w.w = o[3];
    *reinterpret_cast<uint4*>(row + c0) = w;
}

// ---------------------------------------------------------------------------
extern "C" void kernel_launch(void* const* d_in, const int* in_sizes, int n_in,
                              void* d_out, int out_size, void* d_ws, size_t ws_size,
                              hipStream_t stream) {
    const float* x  = (const float*)d_in[0];
    const float* Wq = (const float*)d_in[1];
    const float* Wk = (const float*)d_in[2];
    const float* Wv = (const float*)d_in[3];
    const int*   dk = (const int*)d_in[4];
    float* out = (float*)d_out;
    char* ws = (char*)d_ws;

    const size_t SZ_XE = (size_t)Mc * Ec * 2;  // 32 MiB
    const size_t SZ_W  = (size_t)Ec * Hc * 2;  // 2 MiB

    size_t o = 0;
    auto nxt = [&](size_t bytes) { void* p = ws + o; o += bytes; return p; };
    __bf16* Xh   = (__bf16*)nxt(SZ_XE);
    __bf16* Xl   = (__bf16*)nxt(SZ_XE);
    __bf16* WqhT = (__bf16*)nxt(SZ_W);
    __bf16* WqlT = (__bf16*)nxt(SZ_W);
    __bf16* WkhT = (__bf16*)nxt(SZ_W);
    __bf16* WklT = (__bf16*)nxt(SZ_W);
    __bf16* WvhT = (__bf16*)nxt(SZ_W);
    __bf16* Qh   = (__bf16*)nxt(SZ_XE);
    __bf16* Ql   = (__bf16*)nxt(SZ_XE);
    __bf16* Kh   = (__bf16*)nxt(SZ_XE);
    __bf16* Kl   = (__bf16*)nxt(SZ_XE);
    __bf16* Vt   = (__bf16*)nxt(SZ_XE);
    // S: all-batch f16 [8][2048][2048] = 64 MiB, aliases Xh+Xl (dead after projections)
    unsigned short* S = (unsigned short*)Xh;
    (void)ws_size; (void)in_sizes; (void)n_in; (void)out_size;

    prep_x<<<(Mc * Ec / 4 + 255) / 256, 256, 0, stream>>>(x, Xh, Xl, Mc * Ec);
    prep_w<<<dim3(32, 32, 3), 256, 0, stream>>>(Wq, Wk, Wv, WqhT, WqlT, WkhT, WklT, WvhT);

    // Q/K projections: virtual K=3072 ([Xh|Xl|Xh] x [Wh|Wh|Wl]), hi/lo bf16 out
    gemm8<3, 0><<<dim3(4, 64), 512, 0, stream>>>(
        Xh, Xl, WqhT, WqlT, Qh, Ql, dk, Ec, Ec, 0, 0, 0, 96, 1);
    gemm8<3, 0><<<dim3(4, 64), 512, 0, stream>>>(
        Xh, Xl, WkhT, WklT, Kh, Kl, dk, Ec, Ec, 0, 0, 0, 96, 1);
    // V projection: 1-term, transposed store Vt[b][dout][t]
    gemm8<1, 1><<<dim3(4, 64), 512, 0, stream>>>(
        Xh, nullptr, WvhT, nullptr, Vt, nullptr, dk, Ec, Ec, 0, 0, 0, 32, 1);

    // energy: all batches, causal tiles only, f16 logits, virtual K=3072
    gemm8<3, 2><<<dim3(8, 8, Bc), 512, 0, stream>>>(
        Qh, Ql, Kh, Kl, S, nullptr, dk, Hc, Hc,
        (size_t)Tc * Hc, (size_t)Tc * Hc, (size_t)Tc * Tc, 96, 0);

    softmax_k<<<Bc * Tc, 256, 0, stream>>>(S);

    // PV: all batches, nkt=(by+1)*8 (P beyond causal edge is 0)
    gemm8<1, 3><<<dim3(4, 8, Bc), 512, 0, stream>>>(
        (const __bf16*)S, nullptr, Vt, nullptr, out, nullptr, dk, Tc, Tc,
        (size_t)Tc * Tc, (size_t)Hc * Tc, (size_t)Tc * Hc, 0, 0);
}

// Round 5
// 531.620 us; speedup vs baseline: 4.5387x; 1.0181x over previous
//
#include <hip/hip_runtime.h>

#define DEV __device__ __forceinline__

using f32x4  = __attribute__((ext_vector_type(4))) float;
using bf16x8 = __attribute__((ext_vector_type(8))) __bf16;
using bf16x4 = __attribute__((ext_vector_type(4))) __bf16;

constexpr int Bc = 8, Tc = 2048, Ec = 1024, Hc = 1024;
constexpr int Mc = Bc * Tc;  // 16384 total rows

DEV f32x4 mfma16(bf16x8 a, bf16x8 b, f32x4 c) {
    return __builtin_amdgcn_mfma_f32_16x16x32_bf16(a, b, c, 0, 0, 0);
}
DEV unsigned short f16bits(float f) { return __builtin_bit_cast(unsigned short, (_Float16)f); }
DEV float f16val(unsigned short u) { return (float)__builtin_bit_cast(_Float16, u); }
DEV unsigned short bf16bits(float f) { return __builtin_bit_cast(unsigned short, (__bf16)f); }

// async global->LDS, 16B per lane. LDS dest must be wave-uniform base; HW adds lane*16.
DEV void gload16(const __bf16* g, __bf16* l) {
    __builtin_amdgcn_global_load_lds(
        (const __attribute__((address_space(1))) unsigned int*)g,
        (__attribute__((address_space(3))) unsigned int*)l, 16, 0, 0);
}

// Paired-row swizzled LDS slice layout (per 256x32 bf16 slice = 16KB):
// LDS row r (128B) holds tile-rows {2r, 2r+1} (32 cols each); the 8 16B slots
// within row r are XOR-permuted by (r&7).  Element offset for (tile-row R,
// k-chunk lk [8 elems]):
DEV int swz_off(int R, int lk) {
    return ((R >> 1) << 6) + ((((((R & 1) << 2) | lk) ^ ((R >> 1) & 7))) << 3);
}

// ---------------------------------------------------------------------------
// prep_x: split f32 x into hi/lo bf16 (x = hi + lo to ~17 mantissa bits)
// ---------------------------------------------------------------------------
__global__ __launch_bounds__(256) void prep_x(const float* __restrict__ x,
                                              __bf16* __restrict__ xh,
                                              __bf16* __restrict__ xl, int n) {
    int i = (blockIdx.x * 256 + threadIdx.x) * 4;
    if (i >= n) return;
    f32x4 v = *reinterpret_cast<const f32x4*>(x + i);
    bf16x4 h, l;
#pragma unroll
    for (int j = 0; j < 4; j++) {
        __bf16 hv = (__bf16)v[j];
        h[j] = hv;
        l[j] = (__bf16)(v[j] - (float)hv);
    }
    *reinterpret_cast<bf16x4*>(xh + i) = h;
    *reinterpret_cast<bf16x4*>(xl + i) = l;
}

// ---------------------------------------------------------------------------
// prep_w: transpose W[e][n] -> WT[n][e] and split hi/lo bf16 (V: hi only).
// ---------------------------------------------------------------------------
__global__ __launch_bounds__(256) void prep_w(const float* __restrict__ wq,
                                              const float* __restrict__ wk,
                                              const float* __restrict__ wv,
                                              __bf16* __restrict__ qh, __bf16* __restrict__ ql,
                                              __bf16* __restrict__ kh, __bf16* __restrict__ kl,
                                              __bf16* __restrict__ vh) {
    __shared__ float tile[32][33];
    const int z = blockIdx.z;
    const float* src = (z == 0) ? wq : (z == 1) ? wk : wv;
    __bf16* dh = (z == 0) ? qh : (z == 1) ? kh : vh;
    __bf16* dl = (z == 0) ? ql : (z == 1) ? kl : nullptr;
    const int n0 = blockIdx.x * 32, e0 = blockIdx.y * 32;
    const int tx = threadIdx.x & 31, ty = threadIdx.x >> 5;  // 32 x 8
#pragma unroll
    for (int j = 0; j < 32; j += 8)
        tile[ty + j][tx] = src[(size_t)(e0 + ty + j) * Hc + n0 + tx];
    __syncthreads();
#pragma unroll
    for (int j = 0; j < 32; j += 8) {
        float v = tile[tx][ty + j];
        __bf16 h = (__bf16)v;
        size_t idx = (size_t)(n0 + ty + j) * Ec + e0 + tx;
        dh[idx] = h;
        if (dl) dl[idx] = (__bf16)(v - (float)h);
    }
}

// ---------------------------------------------------------------------------
// gemm8: 256x256 tile, 8 waves (2x4, each 128x64), 512 threads, BK-slice = 32.
// 4-slot LDS ring (A+B 32KB per slot, 128KB total), swizzled paired-row
// layout (bank-conflict-free b128 reads).  Phase P: {vmcnt(8); s_barrier;
// ds_read slice P (12xb128, split 8+4); stage slice P+3 (4x global_load_lds,
// inverse-swizzled global src, linear LDS dst); setprio(1); 2x16 MFMA;
// setprio(0)}.  vmcnt counted; never 0 until the tail.
// Race-freedom: stage at P targets slot (P-1)&3, whose readers' ds_reads are
// lgkmcnt-complete before their MFMAs and barrier-separated from P's stage.
// NTERMS==3: virtual K = 3*1024 with per-slice source remap:
//   term0: Ah*Bh, term1: Al*Bh, term2: Ah*Bl  (= full hi/lo 3-term product).
// EPI: 0 = bf16 hi/lo row-major out (Q/K proj)
//      1 = bf16 transposed store Vt[b][n][t] (V proj)
//      2 = f16 causal energy * 1/sqrt(dk), tile-skip bx>by
//      3 = f32 row-major (PV), nkt = (by+1)*8
// ---------------------------------------------------------------------------
template <int NTERMS, int EPI>
__global__ __launch_bounds__(512, 2) void gemm8(
        const __bf16* __restrict__ Ah, const __bf16* __restrict__ Al,
        const __bf16* __restrict__ Bh, const __bf16* __restrict__ Bl,
        void* __restrict__ out0, void* __restrict__ out1,
        const int* __restrict__ dkp,
        int lda, int ldb, size_t aBS, size_t bBS, size_t oBS,
        int nkt, int swz) {
    __shared__ __bf16 sA[4][256 * 32];  // 64 KiB
    __shared__ __bf16 sB[4][256 * 32];  // 64 KiB

    int bx = blockIdx.x, by = blockIdx.y;
    if (swz) {  // bijective XCD chunking for grid (4,64): XCD x owns by in [8x, 8x+8)
        const int lin = by * 4 + bx;
        const int w = (lin & 7) * 32 + (lin >> 3);
        by = w >> 2;
        bx = w & 3;
    }
    if (EPI == 2 && bx > by) return;  // upper-triangle energy tiles: softmax masks them
    if (EPI == 3) nkt = (by + 1) * 8;  // causal K extent

    const int z = blockIdx.z;
    Ah += (size_t)z * aBS;
    Bh += (size_t)z * bBS;
    if (NTERMS == 3) { Al += (size_t)z * aBS; Bl += (size_t)z * bBS; }

    const int tid = threadIdx.x;
    const int wave = tid >> 6, lane = tid & 63;
    const int lr = lane & 15, lk = lane >> 4;
    const int wm = wave >> 2, wn = wave & 3;  // 2 x 4 wave grid
    const int m0 = by * 256, n0 = bx * 256;

    // staging constants: lane ll fills LDS slot ll&7 of ldsrow (bi*8 + ll>>3).
    // Inverse swizzle gives the ORIGINAL (tile-row, col) this slot must hold:
    const int so = (lane & 7) ^ (lane >> 3);       // original 16B-slot index
    const int strow = 2 * (lane >> 3) + (so >> 2); // tile-row offset within 16-row grp
    const int stcol = (so & 3) * 8;                // element col offset within 32

    auto stage = [&](int sv) {
        const int slot = sv & 3;
        const __bf16 *as, *bs;
        int kk;
        if (NTERMS == 3) {
            const int term = sv >> 5;
            kk = (sv & 31) * 32;
            as = (term == 1) ? Al : Ah;
            bs = (term == 2) ? Bl : Bh;
        } else {
            as = Ah;
            bs = Bh;
            kk = sv * 32;
        }
#pragma unroll
        for (int l = 0; l < 2; l++) {
            const int bi = wave * 2 + l;  // 16-row group index (0..15)
            gload16(as + (size_t)(m0 + bi * 16 + strow) * lda + kk + stcol,
                    &sA[slot][bi * 512]);
            gload16(bs + (size_t)(n0 + bi * 16 + strow) * ldb + kk + stcol,
                    &sB[slot][bi * 512]);
        }
    };

    f32x4 acc[8][4] = {};

    // prologue: 3 slices in flight
    stage(0);
    stage(1);
    stage(2);

    for (int P = 0; P < nkt; ++P) {
        const int rem = nkt - 1 - P;
        if (rem >= 2)
            asm volatile("s_waitcnt vmcnt(8)" ::: "memory");
        else if (rem == 1)
            asm volatile("s_waitcnt vmcnt(4)" ::: "memory");
        else
            asm volatile("s_waitcnt vmcnt(0)" ::: "memory");
        __builtin_amdgcn_s_barrier();
        __builtin_amdgcn_sched_barrier(0);

        const int slot = P & 3;
        bf16x8 af[8], bfr[4];
#pragma unroll
        for (int mi = 0; mi < 4; mi++)
            af[mi] = *reinterpret_cast<const bf16x8*>(
                &sA[slot][swz_off(wm * 128 + mi * 16 + lr, lk)]);
#pragma unroll
        for (int nj = 0; nj < 4; nj++)
            bfr[nj] = *reinterpret_cast<const bf16x8*>(
                &sB[slot][swz_off(wn * 64 + nj * 16 + lr, lk)]);
#pragma unroll
        for (int mi = 4; mi < 8; mi++)
            af[mi] = *reinterpret_cast<const bf16x8*>(
                &sA[slot][swz_off(wm * 128 + mi * 16 + lr, lk)]);

        if (P + 3 < nkt) stage(P + 3);

        __builtin_amdgcn_s_setprio(1);
#pragma unroll
        for (int mi = 0; mi < 4; mi++)
#pragma unroll
            for (int nj = 0; nj < 4; nj++)
                acc[mi][nj] = mfma16(af[mi], bfr[nj], acc[mi][nj]);
#pragma unroll
        for (int mi = 4; mi < 8; mi++)
#pragma unroll
            for (int nj = 0; nj < 4; nj++)
                acc[mi][nj] = mfma16(af[mi], bfr[nj], acc[mi][nj]);
        __builtin_amdgcn_s_setprio(0);
    }

    float scale = 1.0f;
    if (EPI == 2) scale = 1.0f / sqrtf((float)*dkp);

#pragma unroll
    for (int mi = 0; mi < 8; mi++)
#pragma unroll
        for (int nj = 0; nj < 4; nj++) {
            const int gn = n0 + wn * 64 + nj * 16 + lr;
            if (EPI == 1) {
                const int gm0 = m0 + wm * 128 + mi * 16 + lk * 4;
                const int bb = gm0 >> 11, t = gm0 & (Tc - 1);
                bf16x4 pk;
#pragma unroll
                for (int r = 0; r < 4; r++) pk[r] = (__bf16)acc[mi][nj][r];
                *reinterpret_cast<bf16x4*>(
                    &((__bf16*)out0)[((size_t)(bb * Hc + gn)) * Tc + t]) = pk;
            } else {
#pragma unroll
                for (int r = 0; r < 4; r++) {
                    const int gm = m0 + wm * 128 + mi * 16 + lk * 4 + r;
                    const float v = acc[mi][nj][r];
                    if (EPI == 0) {
                        __bf16 h = (__bf16)v;
                        ((__bf16*)out0)[(size_t)gm * Hc + gn] = h;
                        ((__bf16*)out1)[(size_t)gm * Hc + gn] = (__bf16)(v - (float)h);
                    } else if (EPI == 2) {
                        const float e = (gn > gm) ? -INFINITY : v * scale;
                        ((unsigned short*)out0)[(size_t)z * oBS + (size_t)gm * Tc + gn] =
                            f16bits(e);
                    } else {
                        ((float*)out0)[(size_t)z * oBS + (size_t)gm * Hc + gn] = v;
                    }
                }
            }
        }
}

// ---------------------------------------------------------------------------
// softmax_k: one block per (b,q) row.  Reads f16 logits, writes bf16 P in
// place.  k>q forced to -inf (covers never-written upper tiles); P[k>q]=0.
// ---------------------------------------------------------------------------
__global__ __launch_bounds__(256) void softmax_k(unsigned short* __restrict__ S) {
    const int q = blockIdx.x & (Tc - 1);
    const int b = blockIdx.x >> 11;
    const int tid = threadIdx.x;
    const int c0 = tid * 8;
    unsigned short* row = S + ((size_t)b * Tc + q) * Tc;

    uint4 raw = *reinterpret_cast<const uint4*>(row + c0);
    unsigned u[4] = {raw.x, raw.y, raw.z, raw.w};
    float v[8];
#pragma unroll
    for (int p = 0; p < 4; p++) {
        v[2 * p]     = f16val((unsigned short)(u[p] & 0xFFFFu));
        v[2 * p + 1] = f16val((unsigned short)(u[p] >> 16));
    }
#pragma unroll
    for (int i = 0; i < 8; i++)
        if (c0 + i > q) v[i] = -INFINITY;

    float m = v[0];
#pragma unroll
    for (int i = 1; i < 8; i++) m = fmaxf(m, v[i]);
#pragma unroll
    for (int off = 1; off < 64; off <<= 1) m = fmaxf(m, __shfl_xor(m, off));
    __shared__ float red[4];
    if ((tid & 63) == 0) red[tid >> 6] = m;
    __syncthreads();
    m = fmaxf(fmaxf(red[0], red[1]), fmaxf(red[2], red[3]));

    float e[8], s = 0.f;
#pragma unroll
    for (int i = 0; i < 8; i++) {
        e[i] = __expf(v[i] - m);  // exp(-inf)=0
        s += e[i];
    }
#pragma unroll
    for (int off = 1; off < 64; off <<= 1) s += __shfl_xor(s, off);
    __syncthreads();
    if ((tid & 63) == 0) red[tid >> 6] = s;
    __syncthreads();
    s = red[0] + red[1] + red[2] + red[3];
    const float inv = 1.0f / s;

    unsigned o[4];
#pragma unroll
    for (int p = 0; p < 4; p++) {
        unsigned short a = bf16bits(e[2 * p] * inv);
        unsigned short bb = bf16bits(e[2 * p + 1] * inv);
        o[p] = (unsigned)a | ((unsigned)bb << 16);
    }
    uint4 w; w.x = o[0]; w.y = o[1]; w.z = o[2]; w.w = o[3];
    *reinterpret_cast<uint4*>(row + c0) = w;
}

// ---------------------------------------------------------------------------
extern "C" void kernel_launch(void* const* d_in, const int* in_sizes, int n_in,
                              void* d_out, int out_size, void* d_ws, size_t ws_size,
                              hipStream_t stream) {
    const float* x  = (const float*)d_in[0];
    const float* Wq = (const float*)d_in[1];
    const float* Wk = (const float*)d_in[2];
    const float* Wv = (const float*)d_in[3];
    const int*   dk = (const int*)d_in[4];
    float* out = (float*)d_out;
    char* ws = (char*)d_ws;

    const size_t SZ_XE = (size_t)Mc * Ec * 2;  // 32 MiB
    const size_t SZ_W  = (size_t)Ec * Hc * 2;  // 2 MiB

    size_t o = 0;
    auto nxt = [&](size_t bytes) { void* p = ws + o; o += bytes; return p; };
    __bf16* Xh   = (__bf16*)nxt(SZ_XE);
    __bf16* Xl   = (__bf16*)nxt(SZ_XE);
    __bf16* WqhT = (__bf16*)nxt(SZ_W);
    __bf16* WqlT = (__bf16*)nxt(SZ_W);
    __bf16* WkhT = (__bf16*)nxt(SZ_W);
    __bf16* WklT = (__bf16*)nxt(SZ_W);
    __bf16* WvhT = (__bf16*)nxt(SZ_W);
    __bf16* Qh   = (__bf16*)nxt(SZ_XE);
    __bf16* Ql   = (__bf16*)nxt(SZ_XE);
    __bf16* Kh   = (__bf16*)nxt(SZ_XE);
    __bf16* Kl   = (__bf16*)nxt(SZ_XE);
    __bf16* Vt   = (__bf16*)nxt(SZ_XE);
    // S: all-batch f16 [8][2048][2048] = 64 MiB, aliases Xh+Xl (dead after projections)
    unsigned short* S = (unsigned short*)Xh;
    (void)ws_size; (void)in_sizes; (void)n_in; (void)out_size;

    prep_x<<<(Mc * Ec / 4 + 255) / 256, 256, 0, stream>>>(x, Xh, Xl, Mc * Ec);
    prep_w<<<dim3(32, 32, 3), 256, 0, stream>>>(Wq, Wk, Wv, WqhT, WqlT, WkhT, WklT, WvhT);

    // Q/K projections: virtual K=3072 ([Xh|Xl|Xh] x [Wh|Wh|Wl]), hi/lo bf16 out
    gemm8<3, 0><<<dim3(4, 64), 512, 0, stream>>>(
        Xh, Xl, WqhT, WqlT, Qh, Ql, dk, Ec, Ec, 0, 0, 0, 96, 1);
    gemm8<3, 0><<<dim3(4, 64), 512, 0, stream>>>(
        Xh, Xl, WkhT, WklT, Kh, Kl, dk, Ec, Ec, 0, 0, 0, 96, 1);
    // V projection: 1-term, transposed store Vt[b][dout][t]
    gemm8<1, 1><<<dim3(4, 64), 512, 0, stream>>>(
        Xh, nullptr, WvhT, nullptr, Vt, nullptr, dk, Ec, Ec, 0, 0, 0, 32, 1);

    // energy: all batches, causal tiles only, f16 logits, virtual K=3072
    gemm8<3, 2><<<dim3(8, 8, Bc), 512, 0, stream>>>(
        Qh, Ql, Kh, Kl, S, nullptr, dk, Hc, Hc,
        (size_t)Tc * Hc, (size_t)Tc * Hc, (size_t)Tc * Tc, 96, 0);

    softmax_k<<<Bc * Tc, 256, 0, stream>>>(S);

    // PV: all batches, nkt=(by+1)*8 (P beyond causal edge is 0)
    gemm8<1, 3><<<dim3(4, 8, Bc), 512, 0, stream>>>(
        (const __bf16*)S, nullptr, Vt, nullptr, out, nullptr, dk, Tc, Tc,
        (size_t)Tc * Tc, (size_t)Hc * Tc, (size_t)Tc * Hc, 0, 0);
}